// Round 1
// baseline (514.797 us; speedup 1.0000x reference)
//
#include <hip/hip_runtime.h>
#include <hip/hip_bf16.h>

#define TOKENS 16384
#define DMODEL 4096
#define NCH 8
#define CH 512
#define BM 64

typedef short s16x8 __attribute__((ext_vector_type(8)));
typedef float f32x4 __attribute__((ext_vector_type(4)));

__device__ __forceinline__ unsigned short f2bf(float f) {
    unsigned u = __float_as_uint(f);
    u += 0x7fffu + ((u >> 16) & 1u);
    return (unsigned short)(u >> 16);
}

// ---------------------------------------------------------------------------
// K0: weight prep. in: fp32 [n][c][d]  ->  out: bf16 [n][d][c] (transposed)
// ---------------------------------------------------------------------------
__global__ __launch_bounds__(256)
void wprep_kernel(const float* __restrict__ w1, const float* __restrict__ w2,
                  unsigned short* __restrict__ w1t, unsigned short* __restrict__ w2t)
{
    __shared__ float tile[32][33];
    const int which = blockIdx.z >> 3;
    const int n     = blockIdx.z & 7;
    const float*          src = (which ? w2 : w1) + (size_t)n * CH * CH;
    unsigned short*       dst = (which ? w2t : w1t) + (size_t)n * CH * CH;
    const int c0 = blockIdx.y * 32;
    const int d0 = blockIdx.x * 32;
    const int tx = threadIdx.x;   // 0..31 (d within tile on load)
    const int ty = threadIdx.y;   // 0..7
#pragma unroll
    for (int i = 0; i < 32; i += 8)
        tile[ty + i][tx] = src[(size_t)(c0 + ty + i) * CH + d0 + tx];
    __syncthreads();
#pragma unroll
    for (int i = 0; i < 32; i += 8)
        dst[(size_t)(d0 + ty + i) * CH + c0 + tx] = f2bf(tile[tx][ty + i]);
}

// ---------------------------------------------------------------------------
// K1: fused chunk MLP.  grid = (TOKENS/BM, NCH), block = 256 (4 waves).
// Each wave owns a 128-wide N slice of the 512-wide chunk.
// LDS buffer (64KB) holds Xc bf16 (GEMM1 A), then gelu(H1) bf16 (GEMM2 A),
// both XOR-swizzled: byte ^= (row&7)<<4 to break ds_read_b128 bank conflicts.
// Writes pre-LN out' = gelu(Xc@W1 + b1)@W2 + b2 + x  (fp32) into `mid`.
// ---------------------------------------------------------------------------
__global__ __launch_bounds__(256, 2)
void mlp_kernel(const float* __restrict__ x,
                const unsigned short* __restrict__ w1t,
                const unsigned short* __restrict__ w2t,
                const float* __restrict__ b1,
                const float* __restrict__ b2,
                float* __restrict__ mid)
{
    __shared__ unsigned char lds[BM * CH * 2];   // 64 KB, Xc then H1
    const int tile = blockIdx.x;
    const int n    = blockIdx.y;
    const int tid  = threadIdx.x;
    const int wid  = tid >> 6;
    const int lane = tid & 63;
    const int row0 = tile * BM;

    // ---- stage Xc (fp32 -> bf16, swizzled) ----
    {
        const float* xc = x + (size_t)row0 * DMODEL + n * CH;
#pragma unroll
        for (int it = 0; it < 32; ++it) {
            int f = it * 256 + tid;          // float4 index, 128 per row
            int r = f >> 7;
            int c = (f & 127) << 2;
            const float4 v = *(const float4*)(xc + (size_t)r * DMODEL + c);
            unsigned lo = (unsigned)f2bf(v.x) | ((unsigned)f2bf(v.y) << 16);
            unsigned hi = (unsigned)f2bf(v.z) | ((unsigned)f2bf(v.w) << 16);
            int byte = ((r * CH + c) * 2) ^ ((r & 7) << 4);
            *(uint2*)(lds + byte) = make_uint2(lo, hi);
        }
    }
    __syncthreads();

    const int nwoff = wid * 128;       // wave's N offset within the chunk
    const int l15   = lane & 15;
    const int kg    = lane >> 4;       // 0..3

    float b1v[8], b2v[8];
#pragma unroll
    for (int ni = 0; ni < 8; ++ni) {
        int col = nwoff + ni * 16 + l15;
        b1v[ni] = b1[n * CH + col];
        b2v[ni] = b2[n * CH + col];
    }

    f32x4 acc[4][8];
#pragma unroll
    for (int mi = 0; mi < 4; ++mi)
#pragma unroll
        for (int ni = 0; ni < 8; ++ni)
            acc[mi][ni] = (f32x4){0.f, 0.f, 0.f, 0.f};

    // ---- GEMM1: H1 = Xc @ W1  (B streamed from L2: w1t[n][d][c]) ----
    const size_t wb1 = (size_t)n * CH * CH;
#pragma unroll 1
    for (int kt = 0; kt < 16; ++kt) {
        s16x8 bfrag[8];
#pragma unroll
        for (int ni = 0; ni < 8; ++ni) {
            size_t off = wb1 + (size_t)(nwoff + ni * 16 + l15) * CH + kg * 8 + kt * 32;
            bfrag[ni] = *(const s16x8*)(w1t + off);
        }
        s16x8 afrag[4];
#pragma unroll
        for (int mi = 0; mi < 4; ++mi) {
            int r = mi * 16 + l15;
            int byte = ((r * CH + kg * 8 + kt * 32) * 2) ^ ((r & 7) << 4);
            afrag[mi] = *(const s16x8*)(lds + byte);
        }
#pragma unroll
        for (int ni = 0; ni < 8; ++ni)
#pragma unroll
            for (int mi = 0; mi < 4; ++mi)
                acc[mi][ni] = __builtin_amdgcn_mfma_f32_16x16x32_bf16(afrag[mi], bfrag[ni], acc[mi][ni], 0, 0, 0);
    }

    __syncthreads();   // all waves done reading Xc

    // ---- bias1 + exact GELU -> H1 bf16 into (aliased) LDS ----
#pragma unroll
    for (int mi = 0; mi < 4; ++mi)
#pragma unroll
        for (int ni = 0; ni < 8; ++ni)
#pragma unroll
            for (int r = 0; r < 4; ++r) {
                float v = acc[mi][ni][r] + b1v[ni];
                v = 0.5f * v * (1.0f + erff(v * 0.70710678118654752f));
                int row  = mi * 16 + kg * 4 + r;
                int col  = nwoff + ni * 16 + l15;
                int byte = ((row * CH + col) * 2) ^ ((row & 7) << 4);
                *(unsigned short*)(lds + byte) = f2bf(v);
            }
    __syncthreads();

    // ---- GEMM2: H2 = H1 @ W2 ----
#pragma unroll
    for (int mi = 0; mi < 4; ++mi)
#pragma unroll
        for (int ni = 0; ni < 8; ++ni)
            acc[mi][ni] = (f32x4){0.f, 0.f, 0.f, 0.f};

    const size_t wb2 = (size_t)n * CH * CH;
#pragma unroll 1
    for (int kt = 0; kt < 16; ++kt) {
        s16x8 bfrag[8];
#pragma unroll
        for (int ni = 0; ni < 8; ++ni) {
            size_t off = wb2 + (size_t)(nwoff + ni * 16 + l15) * CH + kg * 8 + kt * 32;
            bfrag[ni] = *(const s16x8*)(w2t + off);
        }
        s16x8 afrag[4];
#pragma unroll
        for (int mi = 0; mi < 4; ++mi) {
            int r = mi * 16 + l15;
            int byte = ((r * CH + kg * 8 + kt * 32) * 2) ^ ((r & 7) << 4);
            afrag[mi] = *(const s16x8*)(lds + byte);
        }
#pragma unroll
        for (int ni = 0; ni < 8; ++ni)
#pragma unroll
            for (int mi = 0; mi < 4; ++mi)
                acc[mi][ni] = __builtin_amdgcn_mfma_f32_16x16x32_bf16(afrag[mi], bfrag[ni], acc[mi][ni], 0, 0, 0);
    }

    // ---- epilogue: + b2 + residual x, store fp32 pre-LN ----
    const float* xr = x   + (size_t)row0 * DMODEL + n * CH;
    float*       mr = mid + (size_t)row0 * DMODEL + n * CH;
#pragma unroll
    for (int mi = 0; mi < 4; ++mi)
#pragma unroll
        for (int ni = 0; ni < 8; ++ni)
#pragma unroll
            for (int r = 0; r < 4; ++r) {
                int row = mi * 16 + kg * 4 + r;
                int col = nwoff + ni * 16 + l15;
                float v = acc[mi][ni][r] + b2v[ni] + xr[(size_t)row * DMODEL + col];
                mr[(size_t)row * DMODEL + col] = v;
            }
}

// ---------------------------------------------------------------------------
// K2: in-place LayerNorm over rows of `out` (pre-LN values written by K1).
// One block per row; row lives in registers; single global read+write.
// ---------------------------------------------------------------------------
__global__ __launch_bounds__(256)
void ln_kernel(float* __restrict__ out,
               const float* __restrict__ g,
               const float* __restrict__ bt)
{
    __shared__ float red[8];
    const int row = blockIdx.x;
    const int tid = threadIdx.x;
    float* p = out + (size_t)row * DMODEL;

    float4 v[4];
    float s = 0.f, ss = 0.f;
#pragma unroll
    for (int i = 0; i < 4; ++i) {
        v[i] = *(const float4*)(p + (i * 256 + tid) * 4);
        s  += v[i].x + v[i].y + v[i].z + v[i].w;
        ss += v[i].x * v[i].x + v[i].y * v[i].y + v[i].z * v[i].z + v[i].w * v[i].w;
    }
#pragma unroll
    for (int o = 32; o > 0; o >>= 1) {
        s  += __shfl_xor(s, o, 64);
        ss += __shfl_xor(ss, o, 64);
    }
    const int wid = tid >> 6, lane = tid & 63;
    if (lane == 0) { red[wid] = s; red[4 + wid] = ss; }
    __syncthreads();
    s  = red[0] + red[1] + red[2] + red[3];
    ss = red[4] + red[5] + red[6] + red[7];
    const float mu   = s * (1.f / DMODEL);
    const float var  = ss * (1.f / DMODEL) - mu * mu;
    const float rstd = rsqrtf(var + 1e-5f);

#pragma unroll
    for (int i = 0; i < 4; ++i) {
        int c = (i * 256 + tid) * 4;
        float4 gv = *(const float4*)(g + c);
        float4 bv = *(const float4*)(bt + c);
        float4 o;
        o.x = (v[i].x - mu) * rstd * gv.x + bv.x;
        o.y = (v[i].y - mu) * rstd * gv.y + bv.y;
        o.z = (v[i].z - mu) * rstd * gv.z + bv.z;
        o.w = (v[i].w - mu) * rstd * gv.w + bv.w;
        *(float4*)(p + c) = o;
    }
}

// ---------------------------------------------------------------------------
extern "C" void kernel_launch(void* const* d_in, const int* in_sizes, int n_in,
                              void* d_out, int out_size, void* d_ws, size_t ws_size,
                              hipStream_t stream)
{
    const float* x    = (const float*)d_in[0];
    const float* w1   = (const float*)d_in[1];
    const float* b1   = (const float*)d_in[2];
    const float* w2   = (const float*)d_in[3];
    const float* b2   = (const float*)d_in[4];
    const float* ln_g = (const float*)d_in[5];
    const float* ln_b = (const float*)d_in[6];
    float* out = (float*)d_out;

    unsigned short* w1t = (unsigned short*)d_ws;                 // 8*512*512 bf16 = 4 MiB
    unsigned short* w2t = w1t + (size_t)NCH * CH * CH;           // + 4 MiB

    wprep_kernel<<<dim3(16, 16, 16), dim3(32, 8), 0, stream>>>(w1, w2, w1t, w2t);
    mlp_kernel<<<dim3(TOKENS / BM, NCH), dim3(256), 0, stream>>>(x, w1t, w2t, b1, b2, out);
    ln_kernel<<<dim3(TOKENS), dim3(256), 0, stream>>>(out, ln_g, ln_b);
}